// Round 6
// baseline (399.628 us; speedup 1.0000x reference)
//
#include <hip/hip_runtime.h>

#define NTOT 65536      // 16*64*64 vectors
#define KC   8192       // codebook size
#define DV   64         // embedding dim
#define ZQN  4194304    // z_q elements
#define MAXC 16         // candidate slots per n
#define NSPLIT 8
#define KSLICE (KC / NSPLIT)   // 1024 codes per slice
#define TH   3e-5f      // dot-space margin: numpy rounding (1.2e-5) +
                        // bf16 screen noise (17 sigma) + ||e||^2 (1e-6)

typedef unsigned int u32;
typedef unsigned short ushort;
typedef short short8 __attribute__((ext_vector_type(8)));   // 8 bf16
typedef float float4v __attribute__((ext_vector_type(4)));  // MFMA acc

__device__ __forceinline__ short f2bf(float x) {           // fp32->bf16 RNE
    u32 u = __float_as_uint(x);
    u32 r = (u + 0x7fffu + ((u >> 16) & 1u)) >> 16;
    return (short)r;
}
// monotone fp32 <-> u32 key for atomicMax
__device__ __forceinline__ u32 fenc(float x) {
    u32 b = __float_as_uint(x);
    return (b & 0x80000000u) ? ~b : (b | 0x80000000u);
}
__device__ __forceinline__ float fdec(u32 k) {
    u32 b = (k & 0x80000000u) ? (k & 0x7fffffffu) : ~k;
    return __uint_as_float(b);
}

// Bit-exact numpy fp32 distance (VERIFIED bit-exact rounds 3/4/5):
// d = fl(fl(A+B) - 2*dot), dot in c_einsum SSE3-baseline order.
__device__ __forceinline__ float exact_d(float A, float B,
                                         const float* __restrict__ zr,
                                         const float* __restrict__ e) {
#pragma clang fp contract(off)
    float u0 = 0.f, u1 = 0.f, u2 = 0.f, u3 = 0.f;
#pragma unroll
    for (int i = 0; i < 4; ++i) {
        const int t = 16 * i;
        u0 = (zr[t+0]*e[t+0]) + ((zr[t+4]*e[t+4]) + ((zr[t+8]*e[t+8]) + ((zr[t+12]*e[t+12]) + u0)));
        u1 = (zr[t+1]*e[t+1]) + ((zr[t+5]*e[t+5]) + ((zr[t+9]*e[t+9]) + ((zr[t+13]*e[t+13]) + u1)));
        u2 = (zr[t+2]*e[t+2]) + ((zr[t+6]*e[t+6]) + ((zr[t+10]*e[t+10]) + ((zr[t+14]*e[t+14]) + u2)));
        u3 = (zr[t+3]*e[t+3]) + ((zr[t+7]*e[t+7]) + ((zr[t+11]*e[t+11]) + ((zr[t+15]*e[t+15]) + u3)));
    }
    float dot = (u0 + u1) + (u2 + u3);
    return (A + B) - (2.0f * dot);
}

// prep: pack emb -> bf16 codebook, ||e_k||^2 (fp64->fp32), zero counters.
__global__ __launch_bounds__(256) void vq_prep(
    const float* __restrict__ emb, float* __restrict__ nrm,
    u32* __restrict__ cnt, u32* __restrict__ dmkey,
    double* __restrict__ lacc, ushort2* __restrict__ ebp) {
    int tid = blockIdx.x * 256 + threadIdx.x;        // 262144 threads
    float a = emb[2 * tid], b = emb[2 * tid + 1];    // 524288 = KC*DV elems
    ushort2 p;
    p.x = (ushort)f2bf(a);
    p.y = (ushort)f2bf(b);
    ebp[tid] = p;
    if (tid < KC) {
        double s = 0.0;
#pragma unroll
        for (int d = 0; d < DV; ++d) {
            double v = (double)emb[(size_t)tid * DV + d];
            s = fma(v, v, s);
        }
        nrm[tid] = (float)s;
    }
    if (tid < NTOT) { cnt[tid] = 0u; dmkey[tid] = 0u; }
    if (tid == 0) *lacc = 0.0;
}

// zb: z -> bf16 rows [n][64] so pass B-frags are two dwordx4 per (ns,t).
// Same f2bf as round 5's in-pass conversion -> bitwise-identical fragments.
__global__ __launch_bounds__(256) void vq_zb(const float* __restrict__ z,
                                             ushort* __restrict__ zb) {
    const int n = blockIdx.x * 256 + threadIdx.x;
    const float* zp = z + (size_t)(n >> 12) * 262144 + (n & 4095);
#pragma unroll
    for (int c8 = 0; c8 < 8; ++c8) {
        short8 v;
#pragma unroll
        for (int j = 0; j < 8; ++j)
            v[j] = f2bf(zp[(size_t)(c8 * 8 + j) * 4096]);  // coalesced per j
        *reinterpret_cast<short8*>(zb + (size_t)n * 64 + c8 * 8) = v;
    }
}

// MFMA screen, LDS-free / barrier-free. A-frags loaded straight from the
// bf16 codebook (16 contiguous bytes per lane; wave covers a contiguous
// 1 KB span -> coalesced, L1-shared across the block's 4 waves).
// MODE 0: per-n max bf16-dot (atomicMax). MODE 1: collect k with
// dot >= dotmax - TH (bitwise-identical MFMA dots across passes).
// mfma_f32_16x16x32_bf16: A[m=lane&15][k=quad*8+j], B[k][n=lane&15],
// C: col=lane&15, row=quad*4+reg  (verified m89/m91/m92 + rounds 5).
template <int MODE>
__global__ __launch_bounds__(256, 6) void vq_pass(
    const ushort* __restrict__ zb, const ushort* __restrict__ eb,
    u32* __restrict__ dmkey, u32* __restrict__ cnt, int* __restrict__ cand) {
    const int tid = threadIdx.x;
    const int lane = tid & 63, wv = tid >> 6;
    const int nblk = blockIdx.x & 255, ks = blockIdx.x >> 8;
    const int nb = nblk * 256 + wv * 64;             // wave's 64 n
    const int col = lane & 15, quad = lane >> 4;
    const int nlo = nb + col;

    // z B-fragments: 8 x dwordx4, held in VGPRs for the whole slice
    short8 zf[4][2];
#pragma unroll
    for (int ns = 0; ns < 4; ++ns)
#pragma unroll
        for (int t = 0; t < 2; ++t)
            zf[ns][t] = *reinterpret_cast<const short8*>(
                zb + (size_t)(nlo + ns * 16) * 64 + t * 32 + quad * 8);

    float rmax[4] = {-1e30f, -1e30f, -1e30f, -1e30f};
    float thr[4];
    if (MODE == 1) {
#pragma unroll
        for (int ns = 0; ns < 4; ++ns)
            thr[ns] = fdec(dmkey[nlo + ns * 16]) - TH;
    }

    const int kbase = ks * KSLICE;
    // lane's A-frag pointer: code row (k + lane&15), dims quad*8..+8
    const ushort* ep = eb + (size_t)(kbase + col) * 64 + quad * 8;

#pragma unroll 2
    for (int k0 = kbase; k0 < kbase + KSLICE; k0 += 16) {
        short8 a0 = *reinterpret_cast<const short8*>(ep);        // dims 0..31
        short8 a1 = *reinterpret_cast<const short8*>(ep + 32);   // dims 32..63
        ep += 16 * 64;
#pragma unroll
        for (int ns = 0; ns < 4; ++ns) {
            float4v acc = {0.f, 0.f, 0.f, 0.f};
            acc = __builtin_amdgcn_mfma_f32_16x16x32_bf16(a0, zf[ns][0], acc, 0, 0, 0);
            acc = __builtin_amdgcn_mfma_f32_16x16x32_bf16(a1, zf[ns][1], acc, 0, 0, 0);
            if (MODE == 0) {
                rmax[ns] = fmaxf(rmax[ns],
                           fmaxf(fmaxf(acc[0], acc[1]), fmaxf(acc[2], acc[3])));
            } else {
                float t4 = thr[ns];
                if (acc[0] >= t4 || acc[1] >= t4 || acc[2] >= t4 || acc[3] >= t4) {
                    int n = nlo + ns * 16;                        // rare path
#pragma unroll
                    for (int r = 0; r < 4; ++r) {
                        if (acc[r] >= t4) {
                            u32 pos = atomicAdd(&cnt[n], 1u);
                            if (pos < MAXC)
                                cand[(size_t)n * MAXC + pos] = k0 + quad * 4 + r;
                        }
                    }
                }
            }
        }
    }
    if (MODE == 0) {
#pragma unroll
        for (int ns = 0; ns < 4; ++ns) {
            float m = rmax[ns];
            m = fmaxf(m, __shfl_xor(m, 16));
            m = fmaxf(m, __shfl_xor(m, 32));
            if (quad == 0) atomicMax(&dmkey[nlo + ns * 16], fenc(m));
        }
    }
}

// E1: exact (numpy-bit-identical) rescore of the candidates -> index.
__global__ __launch_bounds__(256) void vq_e1(
    const float* __restrict__ z, const float* __restrict__ emb,
    const float* __restrict__ nrm, const u32* __restrict__ cnt,
    const int* __restrict__ cand, int* __restrict__ idxw,
    float* __restrict__ out) {
    const int n = blockIdx.x * 256 + threadIdx.x;
    const float* zp = z + (size_t)(n >> 12) * 262144 + (n & 4095);
    float zr[DV];
#pragma unroll
    for (int d = 0; d < DV; ++d) zr[d] = zp[(size_t)d * 4096];
    double ad = 0.0;
#pragma unroll
    for (int d = 0; d < DV; ++d) ad = fma((double)zr[d], (double)zr[d], ad);
    const float A = (float)ad;

    float dmin = 1e30f;
    int kmin = 0;
    u32 c = cnt[n];
    if (c <= MAXC) {
        for (u32 j = 0; j < c; ++j) {                 // unordered -> lex min
            int k = cand[(size_t)n * MAXC + j];
            float d = exact_d(A, nrm[k], zr, emb + (size_t)k * DV);
            if (d < dmin || (d == dmin && k < kmin)) { dmin = d; kmin = k; }
        }
    } else {                                          // overflow: ~never
        for (int k = 0; k < KC; ++k) {
            float d = exact_d(A, nrm[k], zr, emb + (size_t)k * DV);
            if (d < dmin) { dmin = d; kmin = k; }
        }
    }
    idxw[n] = kmin;
    out[(size_t)ZQN + 1 + n] = (float)kmin;
}

// E2: z_q gather-store + loss (overwrites the d_out scratch region last).
__global__ __launch_bounds__(256) void vq_e2(
    const float* __restrict__ z, const float* __restrict__ emb,
    const int* __restrict__ idxw, float* __restrict__ out,
    double* __restrict__ lacc) {
    __shared__ double red[4];
    const int tid = threadIdx.x;
    const int n = blockIdx.x * 256 + tid;
    const int b = n >> 12, hw = n & 4095;
    const int kmin = idxw[n];
    const float* zp = z + (size_t)b * 262144 + hw;
    const float* erow = emb + (size_t)kmin * DV;
    double lsum = 0.0;
#pragma unroll
    for (int c = 0; c < DV; ++c) {
        float v = erow[c];
        out[(size_t)b * 262144 + (size_t)c * 4096 + hw] = v;   // coalesced per c
        double dv = (double)v - (double)zp[(size_t)c * 4096];
        lsum = fma(dv, dv, lsum);
    }
#pragma unroll
    for (int off = 32; off > 0; off >>= 1)
        lsum += __shfl_down(lsum, off, 64);
    if ((tid & 63) == 0) red[tid >> 6] = lsum;
    __syncthreads();
    if (tid == 0)
        atomicAdd(lacc, red[0] + red[1] + red[2] + red[3]);
}

__global__ void vq_fin(const double* __restrict__ lacc, float* __restrict__ out) {
    if (threadIdx.x == 0)
        out[ZQN] = (float)(1.25 * (*lacc) / (double)ZQN);
}

extern "C" void kernel_launch(void* const* d_in, const int* in_sizes, int n_in,
                              void* d_out, int out_size, void* d_ws, size_t ws_size,
                              hipStream_t stream) {
    const float* z   = (const float*)d_in[0];
    const float* emb = (const float*)d_in[1];
    float* out = (float*)d_out;

    // d_out scratch inside the z_q span (16.77 MB), consumed before E2:
    int*    cand = (int*)d_out;                              // 4 MB
    ushort* eb   = (ushort*)((char*)d_out + 4194304);        // 1 MB
    ushort* zb   = (ushort*)((char*)d_out + 5242880);        // 8 MB (ends 13.6 MB)
    // ws scratch (<= 820 KB, under the proven 2.1 MB):
    double* lacc  = (double*)d_ws;
    float*  nrm   = (float*)((char*)d_ws + 64);          // 32 KB
    u32*    dmkey = (u32*)((char*)d_ws + 32832);         // 256 KB
    u32*    cnt   = (u32*)((char*)d_ws + 294976);        // 256 KB
    int*    idxw  = (int*)((char*)d_ws + 557120);        // 256 KB

    vq_prep<<<1024, 256, 0, stream>>>(emb, nrm, cnt, dmkey, lacc, (ushort2*)eb);
    vq_zb<<<NTOT / 256, 256, 0, stream>>>(z, zb);
    vq_pass<0><<<NSPLIT * 256, 256, 0, stream>>>(zb, eb, dmkey, cnt, cand);
    vq_pass<1><<<NSPLIT * 256, 256, 0, stream>>>(zb, eb, dmkey, cnt, cand);
    vq_e1<<<256, 256, 0, stream>>>(z, emb, nrm, cnt, cand, idxw, out);
    vq_e2<<<256, 256, 0, stream>>>(z, emb, idxw, out, lacc);
    vq_fin<<<1, 64, 0, stream>>>(lacc, out);
}

// Round 7
// 347.604 us; speedup vs baseline: 1.1497x; 1.1497x over previous
//
#include <hip/hip_runtime.h>

#define NTOT 65536      // 16*64*64 vectors
#define KC   8192       // codebook size
#define DV   64         // embedding dim
#define ZQN  4194304    // z_q elements
#define NSPL 4          // k-slices
#define KSL  2048       // codes per slice
#define TILE 128        // codes per LDS tile
#define NTILE 16        // tiles per slice
#define LSLOT 16        // lazy-list slots per lane
#define CSLOT 16        // candidate cells per (n, slice)
#define THF   4e-5f     // insert margin (>= filter 36*2^-20 + quant slack)
#define ENCSLACK 36     // filter slack in 2^-20 units (~3.4e-5)

typedef unsigned int u32;
typedef unsigned short ushort;
typedef short short8 __attribute__((ext_vector_type(8)));   // 8 bf16
typedef float float4v __attribute__((ext_vector_type(4)));  // MFMA acc

__device__ __forceinline__ short f2bf(float x) {           // fp32->bf16 RNE
    u32 u = __float_as_uint(x);
    u32 r = (u + 0x7fffu + ((u >> 16) & 1u)) >> 16;
    return (short)r;
}

// Bit-exact numpy fp32 distance (VERIFIED bit-exact rounds 3-6):
// d = fl(fl(A+B) - 2*dot), dot in c_einsum SSE3-baseline order.
__device__ __forceinline__ float exact_d(float A, float B,
                                         const float* __restrict__ zr,
                                         const float* __restrict__ e) {
#pragma clang fp contract(off)
    float u0 = 0.f, u1 = 0.f, u2 = 0.f, u3 = 0.f;
#pragma unroll
    for (int i = 0; i < 4; ++i) {
        const int t = 16 * i;
        u0 = (zr[t+0]*e[t+0]) + ((zr[t+4]*e[t+4]) + ((zr[t+8]*e[t+8]) + ((zr[t+12]*e[t+12]) + u0)));
        u1 = (zr[t+1]*e[t+1]) + ((zr[t+5]*e[t+5]) + ((zr[t+9]*e[t+9]) + ((zr[t+13]*e[t+13]) + u1)));
        u2 = (zr[t+2]*e[t+2]) + ((zr[t+6]*e[t+6]) + ((zr[t+10]*e[t+10]) + ((zr[t+14]*e[t+14]) + u2)));
        u3 = (zr[t+3]*e[t+3]) + ((zr[t+7]*e[t+7]) + ((zr[t+11]*e[t+11]) + ((zr[t+15]*e[t+15]) + u3)));
    }
    float dot = (u0 + u1) + (u2 + u3);
    return (A + B) - (2.0f * dot);
}

// conservative enc16 threshold from rmt (= runmax - THF); monotone fixed-point
__device__ __forceinline__ u32 encthr(float rmt_v) {
    float x = fmaxf(rmt_v, -0.03f) + THF;
    return ((u32)((int)(x * 1048576.0f) + 32768 - ENCSLACK)) << 16;
}

// prep: fragment-order-shuffled bf16 codebook + ||e||^2 + zero cnt/lacc.
// Shuffle: tile t(128 codes), step s(16 codes), half h, lane l=q*16+c ->
// chunk holds code row (t*128+s*16+c), dims h*32+q*8..+8. LDS reads land at
// lane*16 (linear -> conflict-free) after a linear 16KB tile copy.
__global__ __launch_bounds__(256) void vq_prep(
    const float* __restrict__ emb, float* __restrict__ nrm,
    u32* __restrict__ cnt, double* __restrict__ lacc,
    ushort* __restrict__ ebs) {
    const int tid = blockIdx.x * 256 + threadIdx.x;    // 65536 threads
    const int t = tid >> 10, r = tid & 1023;
    const int s = r >> 7, r2 = r & 127, h = r2 >> 6, l = r2 & 63;
    const int q = l >> 4, c = l & 15;
    const float* src = emb + (size_t)((t * 128 + s * 16 + c) * 64 + h * 32 + q * 8);
    short8 v;
#pragma unroll
    for (int j = 0; j < 8; ++j) v[j] = f2bf(src[j]);
    *reinterpret_cast<short8*>(ebs + (size_t)tid * 8) = v;
    ((int4*)cnt)[tid] = make_int4(0, 0, 0, 0);         // 1 MB counters
    if (tid < KC) {
        double sacc = 0.0;
#pragma unroll
        for (int d = 0; d < DV; ++d) {
            double x = (double)emb[(size_t)tid * DV + d];
            sacc = fma(x, x, sacc);
        }
        nrm[tid] = (float)sacc;
    }
    if (tid == 0) *lacc = 0.0;
}

// Single MFMA screen pass with on-the-fly candidate collection.
// Block: 256 n x one 2048-code slice. LDS tile (reg-double-buffered) shared
// by 4 waves. Per (lane,ns,step): cell max m4; insert lazy entry if
// m4 >= runmax - THF (runmax <= slice max -> provable superset of codes
// within TH of the global bf16-dot max). Slice end: filter vs final slice
// max, append surviving cells. mfma_f32_16x16x32_bf16 layouts as verified
// rounds 5/6 (A rows=codes, B cols=n, C col=lane&15 row=quad*4+reg).
__global__ __launch_bounds__(256, 4) void vq_pass(
    const float* __restrict__ z, const ushort* __restrict__ ebs,
    u32* __restrict__ cnt, ushort* __restrict__ cand) {
    __shared__ ushort tileS[TILE * DV];     // 16 KB
    __shared__ u32 lists[256 * 17];         // 17 KB (stride 17: bank spread)
    const int tid = threadIdx.x;
    const int lane = tid & 63, wv = tid >> 6;
    const int nblk = blockIdx.x & 255, ks = blockIdx.x >> 8;
    const int nb = nblk * 256 + wv * 64;
    const int col = lane & 15, quad = lane >> 4;
    const int nlo = nb + col;

    // z B-frags in VGPRs (bitwise-identical conversion to rounds 5/6)
    short8 zf[4][2];
#pragma unroll
    for (int ns = 0; ns < 4; ++ns) {
        int n = nlo + ns * 16;
        const float* zp = z + (size_t)(n >> 12) * 262144 + (n & 4095);
#pragma unroll
        for (int t2 = 0; t2 < 2; ++t2)
#pragma unroll
            for (int j = 0; j < 8; ++j)
                zf[ns][t2][j] = f2bf(zp[(size_t)(t2 * 32 + quad * 8 + j) * 4096]);
    }

    u32* mylist = lists + tid * 17;
    int nins = 0;
    float rmt[4] = {-1e30f, -1e30f, -1e30f, -1e30f};   // runmax - THF, per ns

    const char* gs = (const char*)ebs + (size_t)ks * (KSL * DV * 2);
    int4 pre[4];
#pragma unroll
    for (int j = 0; j < 4; ++j)
        pre[j] = *reinterpret_cast<const int4*>(gs + j * 4096 + tid * 16);

    for (int t = 0; t < NTILE; ++t) {
        __syncthreads();
#pragma unroll
        for (int j = 0; j < 4; ++j)
            *reinterpret_cast<int4*>((char*)tileS + j * 4096 + tid * 16) = pre[j];
        __syncthreads();
        if (t < NTILE - 1) {
#pragma unroll
            for (int j = 0; j < 4; ++j)
                pre[j] = *reinterpret_cast<const int4*>(
                    gs + (size_t)(t + 1) * 16384 + j * 4096 + tid * 16);
        }
#pragma unroll
        for (int s = 0; s < 8; ++s) {
            const char* tb = (const char*)tileS + s * 2048;
            short8 a0 = *reinterpret_cast<const short8*>(tb + lane * 16);
            short8 a1 = *reinterpret_cast<const short8*>(tb + 1024 + lane * 16);
#pragma unroll
            for (int ns = 0; ns < 4; ++ns) {
                float4v acc = {0.f, 0.f, 0.f, 0.f};
                acc = __builtin_amdgcn_mfma_f32_16x16x32_bf16(a0, zf[ns][0], acc, 0, 0, 0);
                acc = __builtin_amdgcn_mfma_f32_16x16x32_bf16(a1, zf[ns][1], acc, 0, 0, 0);
                float m4 = fmaxf(fmaxf(acc[0], acc[1]), fmaxf(acc[2], acc[3]));
                if (m4 >= rmt[ns]) {                    // rare-ish slow path
                    rmt[ns] = fmaxf(rmt[ns], m4 - THF);
                    u32 e = ((u32)((int)(m4 * 1048576.0f) + 32768) << 16)
                          | (u32)((t << 5) | (s << 2) | ns);
                    if (nins == LSLOT) {                // compact stale entries
                        u32 e0 = encthr(rmt[0]), e1 = encthr(rmt[1]);
                        u32 e2 = encthr(rmt[2]), e3 = encthr(rmt[3]);
                        int w = 0;
#pragma unroll
                        for (int i = 0; i < LSLOT; ++i) {
                            u32 ei = mylist[i];
                            int nsi = ei & 3;
                            u32 th2 = nsi == 0 ? e0 : nsi == 1 ? e1
                                    : nsi == 2 ? e2 : e3;
                            if (ei >= th2) { mylist[w] = ei; ++w; }
                        }
                        nins = w;
                    }
                    if (nins < LSLOT) { mylist[nins] = e; ++nins; }
                }
            }
        }
        // share runmax across the 4 quads of each n (tightens future inserts)
#pragma unroll
        for (int q2 = 0; q2 < 4; ++q2) {
            float v = rmt[q2];
            v = fmaxf(v, __shfl_xor(v, 16));
            v = fmaxf(v, __shfl_xor(v, 32));
            rmt[q2] = v;
        }
    }

    // final filter vs slice max, append surviving cells
    u32 f0 = encthr(rmt[0]), f1 = encthr(rmt[1]);
    u32 f2 = encthr(rmt[2]), f3 = encthr(rmt[3]);
    for (int i = 0; i < nins; ++i) {
        u32 ei = mylist[i];
        int nsi = ei & 3;
        u32 th2 = nsi == 0 ? f0 : nsi == 1 ? f1 : nsi == 2 ? f2 : f3;
        if (ei >= th2) {
            int tt = (int)(ei >> 5) & 15, ss = (int)(ei >> 2) & 7;
            int cell = tt * 128 + ss * 16 + quad * 4;   // slice-local, 4 codes
            int n = nlo + nsi * 16;
            u32 pos = atomicAdd(&cnt[(size_t)ks * NTOT + n], 1u);
            if (pos < CSLOT)
                cand[((size_t)ks * NTOT + n) * CSLOT + pos] = (ushort)cell;
        }
    }
}

// E1: exact (numpy-bit-identical) rescore of collected cells -> index.
__global__ __launch_bounds__(256) void vq_e1(
    const float* __restrict__ z, const float* __restrict__ emb,
    const float* __restrict__ nrm, const u32* __restrict__ cnt,
    const ushort* __restrict__ cand, int* __restrict__ idxw,
    float* __restrict__ out) {
    const int n = blockIdx.x * 256 + threadIdx.x;
    const float* zp = z + (size_t)(n >> 12) * 262144 + (n & 4095);
    float zr[DV];
#pragma unroll
    for (int d = 0; d < DV; ++d) zr[d] = zp[(size_t)d * 4096];
    double ad = 0.0;
#pragma unroll
    for (int d = 0; d < DV; ++d) ad = fma((double)zr[d], (double)zr[d], ad);
    const float A = (float)ad;

    float dmin = 1e30f;
    int kmin = 0;
    for (int s = 0; s < NSPL; ++s) {
        u32 c = cnt[(size_t)s * NTOT + n];
        if (c > CSLOT) c = CSLOT;
        for (u32 j = 0; j < c; ++j) {
            int cell = cand[((size_t)s * NTOT + n) * CSLOT + j];
            int base = s * KSL + cell;
#pragma unroll
            for (int r = 0; r < 4; ++r) {
                int k = base + r;
                float d = exact_d(A, nrm[k], zr, emb + (size_t)k * DV);
                if (d < dmin || (d == dmin && k < kmin)) { dmin = d; kmin = k; }
            }
        }
    }
    idxw[n] = kmin;
    out[(size_t)ZQN + 1 + n] = (float)kmin;
}

// E2: z_q gather-store + loss (overwrites d_out scratch region last).
__global__ __launch_bounds__(256) void vq_e2(
    const float* __restrict__ z, const float* __restrict__ emb,
    const int* __restrict__ idxw, float* __restrict__ out,
    double* __restrict__ lacc) {
    __shared__ double red[4];
    const int tid = threadIdx.x;
    const int n = blockIdx.x * 256 + tid;
    const int b = n >> 12, hw = n & 4095;
    const int kmin = idxw[n];
    const float* zp = z + (size_t)b * 262144 + hw;
    const float* erow = emb + (size_t)kmin * DV;
    double lsum = 0.0;
#pragma unroll
    for (int c = 0; c < DV; ++c) {
        float v = erow[c];
        out[(size_t)b * 262144 + (size_t)c * 4096 + hw] = v;   // coalesced per c
        double dv = (double)v - (double)zp[(size_t)c * 4096];
        lsum = fma(dv, dv, lsum);
    }
#pragma unroll
    for (int off = 32; off > 0; off >>= 1)
        lsum += __shfl_down(lsum, off, 64);
    if ((tid & 63) == 0) red[tid >> 6] = lsum;
    __syncthreads();
    if (tid == 0)
        atomicAdd(lacc, red[0] + red[1] + red[2] + red[3]);
}

__global__ void vq_fin(const double* __restrict__ lacc, float* __restrict__ out) {
    if (threadIdx.x == 0)
        out[ZQN] = (float)(1.25 * (*lacc) / (double)ZQN);
}

extern "C" void kernel_launch(void* const* d_in, const int* in_sizes, int n_in,
                              void* d_out, int out_size, void* d_ws, size_t ws_size,
                              hipStream_t stream) {
    const float* z   = (const float*)d_in[0];
    const float* emb = (const float*)d_in[1];
    float* out = (float*)d_out;

    // d_out scratch inside the z_q span, consumed before E2 overwrites:
    ushort* ebs  = (ushort*)d_out;                          // 1 MiB shuffled bf16
    u32*    cnt  = (u32*)((char*)d_out + 1048576);          // 1 MiB counters
    ushort* cand = (ushort*)((char*)d_out + 2097152);       // 8 MiB cells
    // ws scratch (~290 KB, well under proven 2.1 MB):
    double* lacc = (double*)d_ws;
    float*  nrm  = (float*)((char*)d_ws + 64);              // 32 KB
    int*    idxw = (int*)((char*)d_ws + 32832);             // 256 KB

    vq_prep<<<256, 256, 0, stream>>>(emb, nrm, cnt, lacc, ebs);
    vq_pass<<<NSPL * 256, 256, 0, stream>>>(z, ebs, cnt, cand);
    vq_e1<<<256, 256, 0, stream>>>(z, emb, nrm, cnt, cand, idxw, out);
    vq_e2<<<256, 256, 0, stream>>>(z, emb, idxw, out, lacc);
    vq_fin<<<1, 64, 0, stream>>>(lacc, out);
}